// Round 15
// baseline (103.523 us; speedup 1.0000x reference)
//
#include <hip/hip_runtime.h>
#include <math.h>

#define N 8192
#define FIN 256
#define FOUT 64
#define ALPHA 0.2f
#define LOG2E 1.442695040888963f

#define FMPITCH 65                 // u32 words per (w,g) row: +1 pad -> conflict-free
#define FMWORDS (64 * FMPITCH)     // 8 waves * 8 groups
#define SMEM_BYTES 33280           // max(fm 16640, epilogue accbuf 32768) + zbuf 512

typedef float f32x4 __attribute__((ext_vector_type(4)));
typedef _Float16 f16x8 __attribute__((ext_vector_type(8)));

union F16V { uint4 u; f16x8 h; };

__device__ __forceinline__ unsigned pack_f16(float a, float b) {
    union { _Float16 h; unsigned short u; } ca, cb;
    ca.h = (_Float16)a; cb.h = (_Float16)b;      // v_cvt_f16_f32, RNE
    return (unsigned)ca.u | ((unsigned)cb.u << 16);
}
// w' = exp(leaky(e)) * 2^-4  (scale cancels in softmax ratio; keeps f16 in range)
__device__ __forceinline__ float wcalc(unsigned av, float fsr, float g) {
    float e = fsr + g;
    float le = e > 0.f ? e : ALPHA * e;
    float r = __builtin_exp2f(fmaf(le, LOG2E, -4.0f));
    return av != 0u ? r : 0.f;
}

// ---------------- Kernel 1: Wh = h@W -> fsrc/fdst + B_packed (pre-fragmented f16) ----
// Bp[(chunk*4+ft)*64 + lane] = f16(Wh[chunk*32+(lane>>4)*8+e][ft*16+(lane&15)])
__global__ __launch_bounds__(512) void gat_prep(
    const float* __restrict__ h, const float* __restrict__ W,
    const float* __restrict__ a,
    float* __restrict__ fsrc, float* __restrict__ fdst,
    uint4* __restrict__ Bp)
{
    __shared__ float sWh[32][FOUT + 1];
    const int t = threadIdx.x;
    const int f = t & 63;
    const int wq = t >> 6;
    const int row0 = blockIdx.x * 32;
    const int rbase = row0 + wq * 4;

    float acc[4] = {0.f, 0.f, 0.f, 0.f};
    for (int k0 = 0; k0 < FIN; k0 += 4) {
        const float w0 = W[(k0 + 0) * FOUT + f];
        const float w1 = W[(k0 + 1) * FOUT + f];
        const float w2 = W[(k0 + 2) * FOUT + f];
        const float w3 = W[(k0 + 3) * FOUT + f];
#pragma unroll
        for (int rr = 0; rr < 4; ++rr) {
            const float4 hv = *reinterpret_cast<const float4*>(
                &h[(size_t)(rbase + rr) * FIN + k0]);
            acc[rr] = fmaf(hv.x, w0, acc[rr]);
            acc[rr] = fmaf(hv.y, w1, acc[rr]);
            acc[rr] = fmaf(hv.z, w2, acc[rr]);
            acc[rr] = fmaf(hv.w, w3, acc[rr]);
        }
    }
    const float as = a[f], ad = a[FOUT + f];
#pragma unroll
    for (int rr = 0; rr < 4; ++rr) {
        sWh[wq * 4 + rr][f] = acc[rr];
        float fs = acc[rr] * as, fd = acc[rr] * ad;
#pragma unroll
        for (int off = 1; off < 64; off <<= 1) {
            fs += __shfl_xor(fs, off, 64);
            fd += __shfl_xor(fd, off, 64);
        }
        if (f == 0) { fsrc[rbase + rr] = fs; fdst[rbase + rr] = fd; }
    }
    __syncthreads();
    if (t < 256) {
        const int ft = t >> 6;
        const int l = t & 63;
        const int li = l & 15, g = l >> 4;
        float v[8];
#pragma unroll
        for (int e = 0; e < 8; ++e) v[e] = sWh[g * 8 + e][ft * 16 + li];
        uint4 pk;
        pk.x = pack_f16(v[0], v[1]);
        pk.y = pack_f16(v[2], v[3]);
        pk.z = pack_f16(v[4], v[5]);
        pk.w = pack_f16(v[6], v[7]);
        Bp[(size_t)(blockIdx.x * 4 + ft) * 64 + l] = pk;
    }
}

// ---------------- Kernel 2: fused transpose + barrier-free MFMA softmax-PV ----
// Phase 1: coalesced adj stream -> fragment-ordered LDS bitmask (8 ds_write/thr).
// ONE lgkm-only barrier (prefetches stay in flight).
// Phase 2: per-wave barrier-free MFMA loop: masks in registers, fdst broadcast,
// Bp coalesced 16B/lane, depth-2 register prefetch. R13-verified epilogue.
struct Regs { float4 g0, g1; uint4 b0, b1, b2, b3; };

__global__ __launch_bounds__(512, 4) void gat_main(
    const int* __restrict__ adj,
    const uint4* __restrict__ Bp,
    const float* __restrict__ fsrc, const float* __restrict__ fdst,
    float* __restrict__ out)
{
    __shared__ __align__(16) char smem[SMEM_BYTES];

    const int t = threadIdx.x;
    const int l = t & 63;
    const int w = t >> 6;
    const int row0 = blockIdx.x * 16;
    unsigned* fm = reinterpret_cast<unsigned*>(smem);

    // ================= PHASE 1: adj -> fm bit-transpose =================
    {
        const int srow = t >> 5;           // 0..15
        const int c5 = t & 31;
        const int c0 = c5 >> 2;            // 0..7
        const int slot = c5 & 3;
        const int lcons = slot * 16 + srow;
        const size_t adjrow = (size_t)(row0 + srow) * N;
#pragma unroll
        for (int w8 = 0; w8 < 8; ++w8) {
            unsigned a32 = 0;
#pragma unroll
            for (int q = 0; q < 4; ++q) {
                const size_t o = adjrow + (w8 * 4 + q) * 256 + c5 * 8;
                const int4 v0 = *reinterpret_cast<const int4*>(&adj[o]);
                const int4 v1 = *reinterpret_cast<const int4*>(&adj[o + 4]);
                unsigned m = 0;
                m |= (v0.x != 0) ? 1u : 0u;
                m |= (v0.y != 0) ? 2u : 0u;
                m |= (v0.z != 0) ? 4u : 0u;
                m |= (v0.w != 0) ? 8u : 0u;
                m |= (v1.x != 0) ? 16u : 0u;
                m |= (v1.y != 0) ? 32u : 0u;
                m |= (v1.z != 0) ? 64u : 0u;
                m |= (v1.w != 0) ? 128u : 0u;
                a32 |= m << (8 * q);
            }
            fm[(w8 * 8 + c0) * FMPITCH + lcons] = a32;
        }
    }

    // ================= PHASE 2: barrier-free MFMA loop =================
    const int r = l & 15;
    const int kg8 = (l >> 4) << 3;
    const int jwbase = w * 1024;
    const int cgbase = w * 32;
    const float fsr = fsrc[row0 + r];

    f32x4 acc0 = {0.f, 0.f, 0.f, 0.f};
    f32x4 acc1 = {0.f, 0.f, 0.f, 0.f};
    f32x4 acc2 = {0.f, 0.f, 0.f, 0.f};
    f32x4 acc3 = {0.f, 0.f, 0.f, 0.f};
    float zacc = 0.f;
    Regs RA, RB;

    // chunk order: c -> cl = (c&3)*8 + (c>>2)  (word g=c>>2, byte q=c&3)
#define CL(c) (((c) & 3) * 8 + ((c) >> 2))

#define LOADG(c, S)                                                            \
    {                                                                          \
        const int cl_ = CL(c);                                                 \
        const int j0_ = jwbase + cl_ * 32;                                     \
        S.g0 = *reinterpret_cast<const float4*>(&fdst[j0_ + kg8]);             \
        S.g1 = *reinterpret_cast<const float4*>(&fdst[j0_ + kg8 + 4]);         \
        const uint4* bp_ = Bp + (size_t)(cgbase + cl_) * 4 * 64 + l;           \
        S.b0 = bp_[0];                                                         \
        S.b1 = bp_[64];                                                        \
        S.b2 = bp_[128];                                                       \
        S.b3 = bp_[192];                                                       \
    }

#define COMPUTE(c, S)                                                          \
    {                                                                          \
        const unsigned m8 = (fmw[(c) >> 2] >> (8 * ((c) & 3))) & 0xffu;        \
        const float w0 = wcalc(m8 & 1u,   fsr, S.g0.x);                        \
        const float w1 = wcalc(m8 & 2u,   fsr, S.g0.y);                        \
        const float w2 = wcalc(m8 & 4u,   fsr, S.g0.z);                        \
        const float w3 = wcalc(m8 & 8u,   fsr, S.g0.w);                        \
        const float w4 = wcalc(m8 & 16u,  fsr, S.g1.x);                        \
        const float w5 = wcalc(m8 & 32u,  fsr, S.g1.y);                        \
        const float w6 = wcalc(m8 & 64u,  fsr, S.g1.z);                        \
        const float w7 = wcalc(m8 & 128u, fsr, S.g1.w);                        \
        zacc += (w0 + w1) + (w2 + w3) + ((w4 + w5) + (w6 + w7));               \
        F16V av, b0v, b1v, b2v, b3v;                                           \
        av.u.x = pack_f16(w0, w1); av.u.y = pack_f16(w2, w3);                  \
        av.u.z = pack_f16(w4, w5); av.u.w = pack_f16(w6, w7);                  \
        b0v.u = S.b0; b1v.u = S.b1; b2v.u = S.b2; b3v.u = S.b3;                \
        __builtin_amdgcn_s_setprio(1);                                         \
        acc0 = __builtin_amdgcn_mfma_f32_16x16x32_f16(av.h, b0v.h, acc0, 0, 0, 0); \
        acc1 = __builtin_amdgcn_mfma_f32_16x16x32_f16(av.h, b1v.h, acc1, 0, 0, 0); \
        acc2 = __builtin_amdgcn_mfma_f32_16x16x32_f16(av.h, b2v.h, acc2, 0, 0, 0); \
        acc3 = __builtin_amdgcn_mfma_f32_16x16x32_f16(av.h, b3v.h, acc3, 0, 0, 0); \
        __builtin_amdgcn_s_setprio(0);                                         \
    }

    // issue chunk 0/1 global prefetches BEFORE the barrier (stay in flight:
    // barrier waits lgkm only, global loads are wave-private)
    LOADG(0, RA);
    LOADG(1, RB);
    asm volatile("s_waitcnt lgkmcnt(0)" ::: "memory");
    __builtin_amdgcn_s_barrier();

    // masks -> registers (8 ds_read_b32, conflict-free)
    unsigned fmw[8];
#pragma unroll
    for (int g = 0; g < 8; ++g) fmw[g] = fm[(w * 8 + g) * FMPITCH + l];

#pragma unroll
    for (int c = 0; c < 32; c += 2) {
        COMPUTE(c, RA);
        if (c + 2 < 32) LOADG(c + 2, RA);
        COMPUTE(c + 1, RB);
        if (c + 3 < 32) LOADG(c + 3, RB);
    }
#undef LOADG
#undef COMPUTE
#undef CL

    // ================= epilogue (R13-verified) =================
    float* accbuf = reinterpret_cast<float*>(smem);            // [8][4][64][4]
    float* zbuf = reinterpret_cast<float*>(smem + 32768);      // [8][16]
    __shared__ float Zfin[16];

    zacc += __shfl_xor(zacc, 16, 64);
    zacc += __shfl_xor(zacc, 32, 64);
    __syncthreads();           // fm no longer needed; safe to alias
    if (l < 16) zbuf[w * 16 + l] = zacc;
    *reinterpret_cast<f32x4*>(&accbuf[((w * 4 + 0) * 64 + l) * 4]) = acc0;
    *reinterpret_cast<f32x4*>(&accbuf[((w * 4 + 1) * 64 + l) * 4]) = acc1;
    *reinterpret_cast<f32x4*>(&accbuf[((w * 4 + 2) * 64 + l) * 4]) = acc2;
    *reinterpret_cast<f32x4*>(&accbuf[((w * 4 + 3) * 64 + l) * 4]) = acc3;
    __syncthreads();
    if (t < 16) {
        float z = 0.f;
#pragma unroll
        for (int w2 = 0; w2 < 8; ++w2) z += zbuf[w2 * 16 + t];
        Zfin[t] = z;
    }
    __syncthreads();

    // D layout (verified): col = lane&15, row = (lane>>4)*4 + reg
#pragma unroll
    for (int e0 = 0; e0 < 2; ++e0) {
        const int e = t + e0 * 512;
        const int rr = e >> 6, f2 = e & 63;
        const int c = f2 >> 4;
        const int ln = (f2 & 15) | ((rr >> 2) << 4);
        const int rg = rr & 3;
        float s = 0.f;
#pragma unroll
        for (int w2 = 0; w2 < 8; ++w2)
            s += accbuf[((w2 * 4 + c) * 64 + ln) * 4 + rg];
        const float hp = s / Zfin[rr];
        out[(size_t)(row0 + rr) * FOUT + f2] = hp > 0.f ? hp : expm1f(hp);
    }
}

extern "C" void kernel_launch(void* const* d_in, const int* in_sizes, int n_in,
                              void* d_out, int out_size, void* d_ws, size_t ws_size,
                              hipStream_t stream) {
    const float* h   = (const float*)d_in[0];
    const int*   adj = (const int*)d_in[1];
    const float* W   = (const float*)d_in[2];
    const float* a   = (const float*)d_in[3];
    float* out = (float*)d_out;

    float* ws = (float*)d_ws;
    float* fsrc = ws;
    float* fdst = fsrc + N;
    uint4* Bp = (uint4*)(fdst + N);        // FOUT*N f16 = 1 MB, pre-fragmented

    gat_prep<<<dim3(N / 32), dim3(512), 0, stream>>>(h, W, a, fsrc, fdst, Bp);
    gat_main<<<dim3(N / 16), dim3(512), 0, stream>>>(adj, Bp, fsrc, fdst, out);
}

// Round 16
// 98.516 us; speedup vs baseline: 1.0508x; 1.0508x over previous
//
#include <hip/hip_runtime.h>
#include <math.h>

#define N 8192
#define FIN 256
#define FOUT 64
#define ALPHA 0.2f
#define LOG2E 1.442695040888963f

#define MPITCH 260                 // u32 words per mask row in LDS (pad 256->260)
#define SMEM_BYTES 33280           // max(mask 16640, epilogue 32768+512)

typedef float f32x4 __attribute__((ext_vector_type(4)));
typedef _Float16 f16x8 __attribute__((ext_vector_type(8)));

union F16V { uint4 u; f16x8 h; };

__device__ __forceinline__ unsigned pack_f16(float a, float b) {
    union { _Float16 h; unsigned short u; } ca, cb;
    ca.h = (_Float16)a; cb.h = (_Float16)b;      // v_cvt_f16_f32, RNE
    return (unsigned)ca.u | ((unsigned)cb.u << 16);
}
// w' = exp(leaky(e)) * 2^-4  (scale cancels in softmax ratio; keeps f16 in range)
__device__ __forceinline__ float wcalc(unsigned av, float fsr, float g) {
    float e = fsr + g;
    float le = e > 0.f ? e : ALPHA * e;
    float r = __builtin_exp2f(fmaf(le, LOG2E, -4.0f));
    return av != 0u ? r : 0.f;
}

// ---------------- Kernel 1 (fused producer): prep + maskify ----------------
// blocks [0,256): Wh=h@W -> fsrc/fdst + Bp (pre-fragmented f16)  [R13-verified]
// blocks [256,16640): adj -> mask8 row-major bitmask, pure stream [R13-verified]
// Fusing lets the small prep workload hide inside the 256MB adj stream.
__global__ __launch_bounds__(512) void gat_prep(
    const float* __restrict__ h, const float* __restrict__ W,
    const float* __restrict__ a, const int* __restrict__ adj,
    float* __restrict__ fsrc, float* __restrict__ fdst,
    uint4* __restrict__ Bp, unsigned char* __restrict__ mask8)
{
    __shared__ float sWh[32][FOUT + 1];
    const int t = threadIdx.x;

    if (blockIdx.x >= 256) {
        // ---- maskify role ----
        const size_t tid = (size_t)(blockIdx.x - 256) * 512 + t;  // 0..8M-1
        const int4 v0 = *reinterpret_cast<const int4*>(&adj[tid * 8]);
        const int4 v1 = *reinterpret_cast<const int4*>(&adj[tid * 8 + 4]);
        unsigned m = 0;
        m |= (v0.x != 0) ? 1u : 0u;
        m |= (v0.y != 0) ? 2u : 0u;
        m |= (v0.z != 0) ? 4u : 0u;
        m |= (v0.w != 0) ? 8u : 0u;
        m |= (v1.x != 0) ? 16u : 0u;
        m |= (v1.y != 0) ? 32u : 0u;
        m |= (v1.z != 0) ? 64u : 0u;
        m |= (v1.w != 0) ? 128u : 0u;
        mask8[tid] = (unsigned char)m;
        return;
    }

    // ---- prep role ----
    const int f = t & 63;
    const int wq = t >> 6;
    const int row0 = blockIdx.x * 32;
    const int rbase = row0 + wq * 4;

    float acc[4] = {0.f, 0.f, 0.f, 0.f};
    for (int k0 = 0; k0 < FIN; k0 += 4) {
        const float w0 = W[(k0 + 0) * FOUT + f];
        const float w1 = W[(k0 + 1) * FOUT + f];
        const float w2 = W[(k0 + 2) * FOUT + f];
        const float w3 = W[(k0 + 3) * FOUT + f];
#pragma unroll
        for (int rr = 0; rr < 4; ++rr) {
            const float4 hv = *reinterpret_cast<const float4*>(
                &h[(size_t)(rbase + rr) * FIN + k0]);
            acc[rr] = fmaf(hv.x, w0, acc[rr]);
            acc[rr] = fmaf(hv.y, w1, acc[rr]);
            acc[rr] = fmaf(hv.z, w2, acc[rr]);
            acc[rr] = fmaf(hv.w, w3, acc[rr]);
        }
    }
    const float as = a[f], ad = a[FOUT + f];
#pragma unroll
    for (int rr = 0; rr < 4; ++rr) {
        sWh[wq * 4 + rr][f] = acc[rr];
        float fs = acc[rr] * as, fd = acc[rr] * ad;
#pragma unroll
        for (int off = 1; off < 64; off <<= 1) {
            fs += __shfl_xor(fs, off, 64);
            fd += __shfl_xor(fd, off, 64);
        }
        if (f == 0) { fsrc[rbase + rr] = fs; fdst[rbase + rr] = fd; }
    }
    __syncthreads();
    if (t < 256) {
        const int ft = t >> 6;
        const int l = t & 63;
        const int li = l & 15, g = l >> 4;
        float v[8];
#pragma unroll
        for (int e = 0; e < 8; ++e) v[e] = sWh[g * 8 + e][ft * 16 + li];
        uint4 pk;
        pk.x = pack_f16(v[0], v[1]);
        pk.y = pack_f16(v[2], v[3]);
        pk.z = pack_f16(v[4], v[5]);
        pk.w = pack_f16(v[6], v[7]);
        Bp[(size_t)(blockIdx.x * 4 + ft) * 64 + l] = pk;
    }
}

// ---------------- Kernel 2: barrier-free MFMA softmax-PV, LDS mask slab ----
// One coalesced 16KB mask-slab load -> LDS [16][260] u32; per chunk ONE
// broadcast ds_read_b32 (16 addrs, 2-way banks = free). fdst/Bp from L2,
// depth-2 register prefetch, raw lgkm-only barrier. R13/R15-verified epilogue.
struct Regs { unsigned mw; float4 g0, g1; uint4 b0, b1, b2, b3; };

__global__ __launch_bounds__(512, 4) void gat_main(
    const unsigned char* __restrict__ mask8,
    const uint4* __restrict__ Bp,
    const float* __restrict__ fsrc, const float* __restrict__ fdst,
    float* __restrict__ out)
{
    __shared__ __align__(16) char smem[SMEM_BYTES];
    unsigned* M32 = reinterpret_cast<unsigned*>(smem);

    const int t = threadIdx.x;
    const int l = t & 63;
    const int w = t >> 6;
    const int row0 = blockIdx.x * 16;

    const int r = l & 15;
    const int g16 = l >> 4;                // 0..3
    const int kg8 = g16 << 3;
    const int jwbase = w * 1024;
    const int cgbase = w * 32;
    const float fsr = fsrc[row0 + r];
    const int mbase = r * MPITCH + w * 32; // word index; +c per chunk
    const int shft = g16 * 8;

    // ---- mask slab -> LDS (issued FIRST so its vmcnt-wait leaves prefetches alone) ----
    const uint4 s0 = *reinterpret_cast<const uint4*>(&mask8[(size_t)row0 * 1024 + t * 32]);
    const uint4 s1 = *reinterpret_cast<const uint4*>(&mask8[(size_t)row0 * 1024 + t * 32 + 16]);

    f32x4 acc0 = {0.f, 0.f, 0.f, 0.f};
    f32x4 acc1 = {0.f, 0.f, 0.f, 0.f};
    f32x4 acc2 = {0.f, 0.f, 0.f, 0.f};
    f32x4 acc3 = {0.f, 0.f, 0.f, 0.f};
    float zacc = 0.f;
    Regs RA, RB;

#define LOADG(c, S)                                                            \
    {                                                                          \
        const int j0_ = jwbase + (c) * 32;                                     \
        S.g0 = *reinterpret_cast<const float4*>(&fdst[j0_ + kg8]);             \
        S.g1 = *reinterpret_cast<const float4*>(&fdst[j0_ + kg8 + 4]);         \
        const uint4* bp_ = Bp + (size_t)(cgbase + (c)) * 4 * 64 + l;           \
        S.b0 = bp_[0];                                                         \
        S.b1 = bp_[64];                                                        \
        S.b2 = bp_[128];                                                       \
        S.b3 = bp_[192];                                                       \
    }

#define MREAD(c, S) { S.mw = M32[mbase + (c)]; }

#define COMPUTE(S)                                                             \
    {                                                                          \
        const unsigned m8 = (S.mw >> shft) & 0xffu;                            \
        const float w0 = wcalc(m8 & 1u,   fsr, S.g0.x);                        \
        const float w1 = wcalc(m8 & 2u,   fsr, S.g0.y);                        \
        const float w2 = wcalc(m8 & 4u,   fsr, S.g0.z);                        \
        const float w3 = wcalc(m8 & 8u,   fsr, S.g0.w);                        \
        const float w4 = wcalc(m8 & 16u,  fsr, S.g1.x);                        \
        const float w5 = wcalc(m8 & 32u,  fsr, S.g1.y);                        \
        const float w6 = wcalc(m8 & 64u,  fsr, S.g1.z);                        \
        const float w7 = wcalc(m8 & 128u, fsr, S.g1.w);                        \
        zacc += (w0 + w1) + (w2 + w3) + ((w4 + w5) + (w6 + w7));               \
        F16V av, b0v, b1v, b2v, b3v;                                           \
        av.u.x = pack_f16(w0, w1); av.u.y = pack_f16(w2, w3);                  \
        av.u.z = pack_f16(w4, w5); av.u.w = pack_f16(w6, w7);                  \
        b0v.u = S.b0; b1v.u = S.b1; b2v.u = S.b2; b3v.u = S.b3;                \
        __builtin_amdgcn_s_setprio(1);                                         \
        acc0 = __builtin_amdgcn_mfma_f32_16x16x32_f16(av.h, b0v.h, acc0, 0, 0, 0); \
        acc1 = __builtin_amdgcn_mfma_f32_16x16x32_f16(av.h, b1v.h, acc1, 0, 0, 0); \
        acc2 = __builtin_amdgcn_mfma_f32_16x16x32_f16(av.h, b2v.h, acc2, 0, 0, 0); \
        acc3 = __builtin_amdgcn_mfma_f32_16x16x32_f16(av.h, b3v.h, acc3, 0, 0, 0); \
        __builtin_amdgcn_s_setprio(0);                                         \
    }

    // issue chunk 0/1 VMEM prefetches (newer than slab loads in the FIFO:
    // the ds_write's wait on slab data leaves these in flight)
    LOADG(0, RA);
    LOADG(1, RB);

    // slab -> LDS [16][260]: row = t>>5, words (t&31)*8 .. +7
    {
        const int mrow = t >> 5;
        const int w0i = (t & 31) * 8;
        char* dst = smem + (mrow * MPITCH + w0i) * 4;
        *reinterpret_cast<uint4*>(dst) = s0;
        *reinterpret_cast<uint4*>(dst + 16) = s1;
    }
    asm volatile("s_waitcnt lgkmcnt(0)" ::: "memory");
    __builtin_amdgcn_s_barrier();

    MREAD(0, RA);
    MREAD(1, RB);
#pragma unroll
    for (int c = 0; c < 32; c += 2) {
        COMPUTE(RA);
        if (c + 2 < 32) { LOADG(c + 2, RA); MREAD(c + 2, RA); }
        COMPUTE(RB);
        if (c + 3 < 32) { LOADG(c + 3, RB); MREAD(c + 3, RB); }
    }
#undef LOADG
#undef MREAD
#undef COMPUTE

    // ================= epilogue (R13/R15-verified) =================
    float* accbuf = reinterpret_cast<float*>(smem);            // [8][4][64][4]
    float* zbuf = reinterpret_cast<float*>(smem + 32768);      // [8][16]
    __shared__ float Zfin[16];

    zacc += __shfl_xor(zacc, 16, 64);
    zacc += __shfl_xor(zacc, 32, 64);
    __syncthreads();           // mask slab no longer needed; safe to alias
    if (l < 16) zbuf[w * 16 + l] = zacc;
    *reinterpret_cast<f32x4*>(&accbuf[((w * 4 + 0) * 64 + l) * 4]) = acc0;
    *reinterpret_cast<f32x4*>(&accbuf[((w * 4 + 1) * 64 + l) * 4]) = acc1;
    *reinterpret_cast<f32x4*>(&accbuf[((w * 4 + 2) * 64 + l) * 4]) = acc2;
    *reinterpret_cast<f32x4*>(&accbuf[((w * 4 + 3) * 64 + l) * 4]) = acc3;
    __syncthreads();
    if (t < 16) {
        float z = 0.f;
#pragma unroll
        for (int w2 = 0; w2 < 8; ++w2) z += zbuf[w2 * 16 + t];
        Zfin[t] = z;
    }
    __syncthreads();

    // D layout (verified): col = lane&15, row = (lane>>4)*4 + reg
#pragma unroll
    for (int e0 = 0; e0 < 2; ++e0) {
        const int e = t + e0 * 512;
        const int rr = e >> 6, f2 = e & 63;
        const int c = f2 >> 4;
        const int ln = (f2 & 15) | ((rr >> 2) << 4);
        const int rg = rr & 3;
        float s = 0.f;
#pragma unroll
        for (int w2 = 0; w2 < 8; ++w2)
            s += accbuf[((w2 * 4 + c) * 64 + ln) * 4 + rg];
        const float hp = s / Zfin[rr];
        out[(size_t)(row0 + rr) * FOUT + f2] = hp > 0.f ? hp : expm1f(hp);
    }
}

extern "C" void kernel_launch(void* const* d_in, const int* in_sizes, int n_in,
                              void* d_out, int out_size, void* d_ws, size_t ws_size,
                              hipStream_t stream) {
    const float* h   = (const float*)d_in[0];
    const int*   adj = (const int*)d_in[1];
    const float* W   = (const float*)d_in[2];
    const float* a   = (const float*)d_in[3];
    float* out = (float*)d_out;

    float* ws = (float*)d_ws;
    float* fsrc = ws;                              // 8192 f32
    float* fdst = fsrc + N;                        // 8192 f32
    uint4* Bp = (uint4*)(fdst + N);                // 65536 uint4 = 1 MB
    unsigned char* mask8 = (unsigned char*)(Bp + 65536);   // 8 MB row-major

    gat_prep<<<dim3(256 + 16384), dim3(512), 0, stream>>>(
        h, W, a, adj, fsrc, fdst, Bp, mask8);
    gat_main<<<dim3(N / 16), dim3(512), 0, stream>>>(
        mask8, Bp, fsrc, fdst, out);
}